// Round 3
// baseline (260.274 us; speedup 1.0000x reference)
//
#include <hip/hip_runtime.h>

#define GAMMA 0.01f
#define B 32
#define G 2048
#define C 16
#define S 8
#define L 3
#define M 16
#define NBLK 256
#define NTHR 256

// lse in base-2: exp(v/g) = exp2(v * K_EXP); g*log(s) = K_LOG * log2(s)
#define K_EXP 144.26950408889634f     // log2(e) / GAMMA
#define K_LOG 0.006931471805599453f   // GAMMA * ln(2)

__device__ __forceinline__ float waveMax(float v) {
#pragma unroll
    for (int off = 32; off > 0; off >>= 1)
        v = fmaxf(v, __shfl_xor(v, off, 64));
    return v;
}

// 256-thread (4-wave) block max, broadcast. Leading sync guards scratch reuse.
__device__ __forceinline__ float blockMaxBcast(float v, float* scratch) {
    float wm = waveMax(v);
    __syncthreads();
    if ((threadIdx.x & 63) == 0) scratch[threadIdx.x >> 6] = wm;
    __syncthreads();
    return fmaxf(fmaxf(scratch[0], scratch[1]), fmaxf(scratch[2], scratch[3]));
}

// Block max -> dst[blockIdx.x] (plain store; published by the next barrier).
__device__ __forceinline__ void blockMaxOut(float v, float* scratch, float* dst) {
    float wm = waveMax(v);
    __syncthreads();
    if ((threadIdx.x & 63) == 0) scratch[threadIdx.x >> 6] = wm;
    __syncthreads();
    if (threadIdx.x == 0)
        dst[blockIdx.x] =
            fmaxf(fmaxf(scratch[0], scratch[1]), fmaxf(scratch[2], scratch[3]));
}

// Hand-rolled sense-style grid barrier, epoch-monotonic within one launch.
// slots[bid*32] (one 128B line per block) zeroed by host memset each replay.
// Arrival: release store (publishes this block's prior writes via wbl2).
// Block 0: 255 threads poll the 255 slots wave-parallel (relaxed), one
// trailing acquire each (L1/L2 inv), then t0 release-publishes gen.
// Spinners: poll gen relaxed + trailing acquire. Guard avoids hard hangs.
__device__ __forceinline__ void gridBarrier(unsigned* slots, unsigned* gen,
                                            int bid, unsigned ep) {
    __syncthreads();
    if (bid == 0) {
        const int t = threadIdx.x;
        if (t > 0) {
            int guard = 0;
            while (__hip_atomic_load(&slots[t * 32], __ATOMIC_RELAXED,
                                     __HIP_MEMORY_SCOPE_AGENT) < ep &&
                   ++guard < (1 << 20)) {}
            (void)__hip_atomic_load(&slots[t * 32], __ATOMIC_ACQUIRE,
                                    __HIP_MEMORY_SCOPE_AGENT);
        }
        __syncthreads();
        if (t == 0)
            __hip_atomic_store(gen, ep, __ATOMIC_RELEASE,
                               __HIP_MEMORY_SCOPE_AGENT);
    } else {
        if (threadIdx.x == 0) {
            __hip_atomic_store(&slots[bid * 32], ep, __ATOMIC_RELEASE,
                               __HIP_MEMORY_SCOPE_AGENT);
            int guard = 0;
            while (__hip_atomic_load(gen, __ATOMIC_RELAXED,
                                     __HIP_MEMORY_SCOPE_AGENT) < ep &&
                   ++guard < (1 << 20)) {}
            (void)__hip_atomic_load(gen, __ATOMIC_ACQUIRE,
                                    __HIP_MEMORY_SCOPE_AGENT);
        }
        __syncthreads();
    }
}

// Persistent cooperative kernel: 256 blocks x 256 threads (1 block/CU).
// Block bid -> (b = bid&31, gt = bid>>5): row b, g in [gt*256, gt*256+256).
// Under round-robin XCD placement, all 8 blocks of row b share bid%8 == b%8
// -> same XCD (perf heuristic only; correctness via agent-scope barrier).
// Thread owns one (b,g) for ALL 16 c's: h[16], hy, ry live in registers
// across phases; only Pm partials (1KB) and Ry rows (256KB) cross blocks.
extern "C" __global__ __launch_bounds__(256) void kmain(
    const float* __restrict__ x, const float* __restrict__ W,
    const int* __restrict__ I,
    unsigned* __restrict__ slots, unsigned* __restrict__ gen,
    unsigned* __restrict__ Ipk, float* __restrict__ Pm1,
    float* __restrict__ Pm2, float* __restrict__ Pm3,
    float* __restrict__ Ry, float* __restrict__ out)
{
    __shared__ __align__(16) float Vrow[G];   // 8 KB: s-scaled V row b
    __shared__ float WsL[C * M];              // transposed softmax(W)
    __shared__ float scratch[4];

    const int t = threadIdx.x;
    const int bid = blockIdx.x;
    const int b = bid & 31;
    const int gt = bid >> 5;
    const int g = (gt << 8) + t;
    const int i = b * G + g;
    unsigned ep = 0;

    // ---- init: per-block Ws (redundant, cheap) + pack I to u16 byte-offs ----
    {
        const int m = t >> 4, c = t & 15;
        float rmax = -INFINITY;
#pragma unroll
        for (int j = 0; j < C; j++) rmax = fmaxf(rmax, W[m * C + j]);
        float rsum = 0.f;
#pragma unroll
        for (int j = 0; j < C; j++) rsum += __expf(W[m * C + j] - rmax);
        WsL[c * M + m] = __expf(W[m * C + c] - rmax) / rsum;   // [c][m]
    }
    {
        const int tid = bid * NTHR + t;       // items (c,g) = 32768: blocks 0-127
        if (tid < C * G) {
            const int4* ip4 = (const int4*)(I + (size_t)tid * 24);
            int idx[24];
#pragma unroll
            for (int j = 0; j < 6; j++) {
                int4 v = ip4[j];
                idx[4 * j + 0] = v.x; idx[4 * j + 1] = v.y;
                idx[4 * j + 2] = v.z; idx[4 * j + 3] = v.w;
            }
            unsigned w[12];
#pragma unroll
            for (int j = 0; j < 12; j++)      // byte offsets (idx*4), packed x2
                w[j] = ((unsigned)idx[2 * j] << 2) | ((unsigned)idx[2 * j + 1] << 18);
            uint4* dst = (uint4*)(Ipk + (size_t)tid * 12);
            dst[0] = make_uint4(w[0], w[1], w[2], w[3]);
            dst[1] = make_uint4(w[4], w[5], w[6], w[7]);
            dst[2] = make_uint4(w[8], w[9], w[10], w[11]);
        }
    }
    gridBarrier(slots, gen, bid, ++ep);

    float ry = 0.f;
    const float* Vsrc = x;
    for (int it = 0; it < 5; it++) {
        // ---------------- phase A: gather + lse_S + fused einsum ----------------
        float s = 1.0f;
        if (it > 0) {                         // uniform branch
            float m3 = blockMaxBcast(Pm3[t], scratch);
            s = (m3 > 1.0f) ? 1.0f / m3 : 1.0f;
        }
        {
            const float4* V4 = (const float4*)(Vsrc + (size_t)b * G);
            float4* Vr4 = (float4*)Vrow;
#pragma unroll
            for (int j = 0; j < 2; j++) {
                float4 v = V4[t + j * 256];
                v.x *= s; v.y *= s; v.z *= s; v.w *= s;
                Vr4[t + j * 256] = v;
            }
        }
        __syncthreads();

        float h[M];
#pragma unroll
        for (int m = 0; m < M; m++) h[m] = 0.f;
        float ymax = -INFINITY;
        const char* vb = (const char*)Vrow;

#pragma unroll 4
        for (int c = 0; c < C; c++) {
            const uint4* ip = (const uint4*)(Ipk + ((size_t)c * G + g) * 12);
            uint4 u0 = ip[0], u1 = ip[1], u2 = ip[2];
            unsigned w[12] = {u0.x, u0.y, u0.z, u0.w, u1.x, u1.y,
                              u1.z, u1.w, u2.x, u2.y, u2.z, u2.w};
            float vv[24];
#pragma unroll
            for (int q = 0; q < 12; q++) {    // 24 random LDS b32 gathers
                vv[2 * q]     = *(const float*)(vb + (w[q] & 0xffffu));
                vv[2 * q + 1] = *(const float*)(vb + (w[q] >> 16));
            }
            float body[S];
#pragma unroll
            for (int ss = 0; ss < S; ss++)
                body[ss] = vv[ss * 3] * vv[ss * 3 + 1] * vv[ss * 3 + 2];
            float bm = body[0];
#pragma unroll
            for (int ss = 1; ss < S; ss++) bm = fmaxf(bm, body[ss]);
            float sum = 0.f;
#pragma unroll
            for (int ss = 0; ss < S; ss++)
                sum += exp2f((body[ss] - bm) * K_EXP);
            float y = fmaf(K_LOG, log2f(sum), bm);   // unscaled Cv
            ymax = fmaxf(ymax, y);
#pragma unroll
            for (int m = 0; m < M; m++)       // s1 deferred (linear)
                h[m] = fmaf(WsL[c * M + m], y, h[m]);
        }
        blockMaxOut(ymax, scratch, Pm1);
        gridBarrier(slots, gen, bid, ++ep);

        // ---------------- phase B: s1-scale + lse_M (registers only) ----------
        float hy;
        {
            float m1 = blockMaxBcast(Pm1[t], scratch);
            float s1 = (m1 > 1.0f) ? 1.0f / m1 : 1.0f;
            float hv[M];
            float hm = -INFINITY;
#pragma unroll
            for (int m = 0; m < M; m++) {
                hv[m] = s1 * h[m];
                hm = fmaxf(hm, hv[m]);
            }
            float sum = 0.f;
#pragma unroll
            for (int m = 0; m < M; m++) sum += exp2f((hv[m] - hm) * K_EXP);
            hy = fmaf(K_LOG, log2f(sum), hm);
            blockMaxOut(hy, scratch, Pm2);
        }
        gridBarrier(slots, gen, bid, ++ep);

        // ---------------- phase C: lse_2 with Rprev from LDS ------------------
        {
            float m2 = blockMaxBcast(Pm2[t], scratch);
            float s2 = (m2 > 1.0f) ? 1.0f / m2 : 1.0f;
            float Rv = Vrow[g];               // = sp * Rprev (already scaled)
            float rv = s2 * hy;
            float a = fmaxf(Rv, rv), d = fminf(Rv, rv);
            ry = fmaf(K_LOG, log2f(1.0f + exp2f((d - a) * K_EXP)), a);
            Ry[i] = ry;                       // next A stages full row b
            blockMaxOut(ry, scratch, Pm3);
        }
        gridBarrier(slots, gen, bid, ++ep);
        Vsrc = Ry;
    }

    // ---------------- output (ry still in register) ----------------
    float m3 = blockMaxBcast(Pm3[t], scratch);
    float sf = (m3 > 1.0f) ? 1.0f / m3 : 1.0f;
    out[i] = sf * ry;
}

extern "C" void kernel_launch(void* const* d_in, const int* in_sizes, int n_in,
                              void* d_out, int out_size, void* d_ws, size_t ws_size,
                              hipStream_t stream) {
    const float* x = (const float*)d_in[0];   // (B,G)
    const float* W = (const float*)d_in[1];   // (M,C)
    const int*   I = (const int*)d_in[2];     // (C,G,S,L)
    float* out = (float*)d_out;

    // workspace layout (u32/f32 units)
    unsigned* slots = (unsigned*)d_ws;                 // 256*32 (128B/block)
    unsigned* gen   = slots + NBLK * 32;               // 1 (+pad to 32)
    float* Pm1 = (float*)(slots + NBLK * 32 + 32);     // 256
    float* Pm2 = Pm1 + NBLK;                           // 256
    float* Pm3 = Pm2 + NBLK;                           // 256
    float* Ry  = Pm3 + NBLK;                           // B*G
    unsigned* Ipk = (unsigned*)(Ry + (size_t)B * G);   // C*G*12 u32 (1.5MB)

    // Zero barrier state every replay (graph-capturable memset node).
    hipMemsetAsync(slots, 0, (NBLK * 32 + 32) * sizeof(unsigned), stream);

    void* args[] = {(void*)&x,   (void*)&W,   (void*)&I,   (void*)&slots,
                    (void*)&gen, (void*)&Ipk, (void*)&Pm1, (void*)&Pm2,
                    (void*)&Pm3, (void*)&Ry,  (void*)&out};
    hipLaunchCooperativeKernel((const void*)kmain, dim3(NBLK), dim3(NTHR),
                               args, 0, stream);
}

// Round 4
// 174.417 us; speedup vs baseline: 1.4922x; 1.4922x over previous
//
#include <hip/hip_runtime.h>

#define GAMMA 0.01f
#define B 32
#define G 2048
#define C 16
#define S 8
#define L 3
#define M 16
#define NBLK 256
#define NTHR 256

// lse in base-2: exp(v/g) = exp2(v * K_EXP); g*log(s) = K_LOG * log2(s)
#define K_EXP 144.26950408889634f     // log2(e) / GAMMA
#define K_LOG 0.006931471805599453f   // GAMMA * ln(2)

#define SCOPE __HIP_MEMORY_SCOPE_AGENT

// Agent-scope relaxed atomics: performed at the L3 coherence point (no L1/L2
// allocation, no fence/flush needed). All cross-block traffic uses these.
__device__ __forceinline__ unsigned ald(const unsigned* p) {
    return __hip_atomic_load(p, __ATOMIC_RELAXED, SCOPE);
}
__device__ __forceinline__ void ast(unsigned* p, unsigned v) {
    __hip_atomic_store(p, v, __ATOMIC_RELAXED, SCOPE);
}
__device__ __forceinline__ float aldf(const float* p) {
    return __hip_atomic_load(p, __ATOMIC_RELAXED, SCOPE);
}
__device__ __forceinline__ void astf(float* p, float v) {
    __hip_atomic_store(p, v, __ATOMIC_RELAXED, SCOPE);
}

__device__ __forceinline__ float waveMax(float v) {
#pragma unroll
    for (int off = 32; off > 0; off >>= 1)
        v = fmaxf(v, __shfl_xor(v, off, 64));
    return v;
}

// 256-thread block max, broadcast. Leading sync guards scratch reuse.
__device__ __forceinline__ float blockMaxBcast(float v, float* scratch) {
    float wm = waveMax(v);
    __syncthreads();
    if ((threadIdx.x & 63) == 0) scratch[threadIdx.x >> 6] = wm;
    __syncthreads();
    return fmaxf(fmaxf(scratch[0], scratch[1]), fmaxf(scratch[2], scratch[3]));
}

// Block max -> dst[bid] via L3 atomic (published by next barrier's vmcnt wait).
__device__ __forceinline__ void blockMaxOut(float v, float* scratch, float* dst) {
    float wm = waveMax(v);
    __syncthreads();
    if ((threadIdx.x & 63) == 0) scratch[threadIdx.x >> 6] = wm;
    __syncthreads();
    if (threadIdx.x == 0)
        astf(&dst[blockIdx.x],
             fmaxf(fmaxf(scratch[0], scratch[1]), fmaxf(scratch[2], scratch[3])));
}

// Fence-free grid barrier (epoch-monotonic within one launch; state zeroed by
// host memset each replay). Arrival: s_waitcnt vmcnt(0) (all prior L3-atomic
// data stores done) + relaxed slot store, one 128B line per block. Block 0
// polls all slots wave-parallel, publishes gen; 16 relay blocks (1..16)
// re-publish to rgen[r]; spinners (>=17) poll rgen[1+(bid&15)] (<=16 pollers
// per line). No acquire/release fences: all shared data moves via L3 atomics,
// so L2 stays warm (Ipk!) across phases. Guards turn bugs into wrong answers
// (caught by verify) instead of hangs.
__device__ __forceinline__ void gridBarrier(unsigned* slots, unsigned* gen,
                                            unsigned* rgen, int bid, unsigned ep) {
    __syncthreads();
    const int t = threadIdx.x;
    if (bid == 0) {
        if (t > 0) {
            int guard = 0;
            while (ald(&slots[t * 32]) < ep && ++guard < (1 << 17)) {}
        }
        __syncthreads();                 // all arrivals observed
        if (t == 0) {
            asm volatile("s_waitcnt vmcnt(0) lgkmcnt(0)" ::: "memory");
            ast(gen, ep);
        }
    } else {
        if (t == 0) {
            asm volatile("s_waitcnt vmcnt(0) lgkmcnt(0)" ::: "memory");
            ast(&slots[bid * 32], ep);
            int guard = 0;
            if (bid <= 16) {             // relay: poll gen, re-publish
                while (ald(gen) < ep && ++guard < (1 << 17)) {}
                ast(&rgen[bid * 32], ep);
            } else {
                const int r = 1 + (bid & 15);
                while (ald(&rgen[r * 32]) < ep && ++guard < (1 << 17)) {}
            }
        }
        __syncthreads();
    }
}

// Persistent kernel, PLAIN launch (graph node): 256 blocks x 256 threads,
// 1 block/CU by construction (9.7KB LDS, ~40 VGPR). Block bid -> (b=bid&31,
// gt=bid>>5). Thread owns one (b,g) for all 16 c's: h[16], hy, ry live in
// registers across phases; cross-block traffic = Pm partials (1KB) + Ry rows.
extern "C" __global__ __launch_bounds__(256) void kmain(
    const float* __restrict__ x, const float* __restrict__ W,
    const int* __restrict__ I,
    unsigned* __restrict__ slots, unsigned* __restrict__ gen,
    unsigned* __restrict__ rgen, unsigned* __restrict__ Ipk,
    float* __restrict__ Pm1, float* __restrict__ Pm2, float* __restrict__ Pm3,
    float* __restrict__ Ry, float* __restrict__ out)
{
    __shared__ __align__(16) float Vrow[G];   // 8 KB: s-scaled V row b
    __shared__ float WsL[C * M];              // transposed softmax(W)
    __shared__ float scratch[4];

    const int t = threadIdx.x;
    const int bid = blockIdx.x;
    const int b = bid & 31;
    const int gt = bid >> 5;
    const int g = (gt << 8) + t;
    const int i = b * G + g;
    unsigned ep = 0;

    // ---- init: per-block Ws (redundant, cheap) + pack I -> byte-offset pairs.
    // Ipk written with L3 atomics (plain stores would sit dirty in one XCD's L2,
    // invisible to fence-free remote readers).
    {
        const int m = t >> 4, c = t & 15;
        float rmax = -INFINITY;
#pragma unroll
        for (int j = 0; j < C; j++) rmax = fmaxf(rmax, W[m * C + j]);
        float rsum = 0.f;
#pragma unroll
        for (int j = 0; j < C; j++) rsum += __expf(W[m * C + j] - rmax);
        WsL[c * M + m] = __expf(W[m * C + c] - rmax) / rsum;   // [c][m]
    }
    {
        const int tid = bid * NTHR + t;       // items (c,g): blocks 0-127
        if (tid < C * G) {
            const int4* ip4 = (const int4*)(I + (size_t)tid * 24);
            int idx[24];
#pragma unroll
            for (int j = 0; j < 6; j++) {
                int4 v = ip4[j];
                idx[4 * j + 0] = v.x; idx[4 * j + 1] = v.y;
                idx[4 * j + 2] = v.z; idx[4 * j + 3] = v.w;
            }
            unsigned* dst = Ipk + (size_t)tid * 12;
#pragma unroll
            for (int j = 0; j < 12; j++)      // byte offsets (idx*4), packed x2
                ast(&dst[j],
                    ((unsigned)idx[2 * j] << 2) | ((unsigned)idx[2 * j + 1] << 18));
        }
    }
    gridBarrier(slots, gen, rgen, bid, ++ep);

    float ry = 0.f;
    for (int it = 0; it < 5; it++) {
        // ---------------- phase A: gather + lse_S + fused einsum --------------
        float s = 1.0f;
        if (it > 0) {                         // uniform branch
            float m3 = blockMaxBcast(aldf(&Pm3[t]), scratch);
            s = (m3 > 1.0f) ? 1.0f / m3 : 1.0f;
        }
        if (it == 0) {                        // x: visible via launch acquire
            const float4* V4 = (const float4*)(x + (size_t)b * G);
            float4* Vr4 = (float4*)Vrow;
#pragma unroll
            for (int j = 0; j < 2; j++) Vr4[t + j * 256] = V4[t + j * 256];
        } else {                              // Ry: L3-atomic reads (coherent)
            const float* src = Ry + (size_t)b * G;
#pragma unroll
            for (int j = 0; j < 8; j++) {
                const int gg = t + j * 256;
                Vrow[gg] = s * aldf(&src[gg]);
            }
        }
        __syncthreads();

        float h[M];
#pragma unroll
        for (int m = 0; m < M; m++) h[m] = 0.f;
        float ymax = -INFINITY;
        const char* vb = (const char*)Vrow;

#pragma unroll 4
        for (int c = 0; c < C; c++) {
            const uint4* ip = (const uint4*)(Ipk + ((size_t)c * G + g) * 12);
            uint4 u0 = ip[0], u1 = ip[1], u2 = ip[2];
            unsigned w[12] = {u0.x, u0.y, u0.z, u0.w, u1.x, u1.y,
                              u1.z, u1.w, u2.x, u2.y, u2.z, u2.w};
            float vv[24];
#pragma unroll
            for (int q = 0; q < 12; q++) {    // 24 random LDS b32 gathers
                vv[2 * q]     = *(const float*)(vb + (w[q] & 0xffffu));
                vv[2 * q + 1] = *(const float*)(vb + (w[q] >> 16));
            }
            float body[S];
#pragma unroll
            for (int ss = 0; ss < S; ss++)
                body[ss] = vv[ss * 3] * vv[ss * 3 + 1] * vv[ss * 3 + 2];
            float bm = body[0];
#pragma unroll
            for (int ss = 1; ss < S; ss++) bm = fmaxf(bm, body[ss]);
            float sum = 0.f;
#pragma unroll
            for (int ss = 0; ss < S; ss++)
                sum += exp2f((body[ss] - bm) * K_EXP);
            float y = fmaf(K_LOG, log2f(sum), bm);   // unscaled Cv
            ymax = fmaxf(ymax, y);
#pragma unroll
            for (int m = 0; m < M; m++)       // s1 deferred (linear)
                h[m] = fmaf(WsL[c * M + m], y, h[m]);
        }
        blockMaxOut(ymax, scratch, Pm1);
        gridBarrier(slots, gen, rgen, bid, ++ep);

        // ---------------- phase B: s1-scale + lse_M (registers only) ----------
        float hy;
        {
            float m1 = blockMaxBcast(aldf(&Pm1[t]), scratch);
            float s1 = (m1 > 1.0f) ? 1.0f / m1 : 1.0f;
            float hv[M];
            float hm = -INFINITY;
#pragma unroll
            for (int m = 0; m < M; m++) {
                hv[m] = s1 * h[m];
                hm = fmaxf(hm, hv[m]);
            }
            float sum = 0.f;
#pragma unroll
            for (int m = 0; m < M; m++) sum += exp2f((hv[m] - hm) * K_EXP);
            hy = fmaf(K_LOG, log2f(sum), hm);
            blockMaxOut(hy, scratch, Pm2);
        }
        gridBarrier(slots, gen, rgen, bid, ++ep);

        // ---------------- phase C: lse_2 with Rprev from LDS ------------------
        {
            float m2 = blockMaxBcast(aldf(&Pm2[t]), scratch);
            float s2 = (m2 > 1.0f) ? 1.0f / m2 : 1.0f;
            float Rv = Vrow[g];               // = sp * Rprev (already scaled)
            float rv = s2 * hy;
            float a = fmaxf(Rv, rv), d = fminf(Rv, rv);
            ry = fmaf(K_LOG, log2f(1.0f + exp2f((d - a) * K_EXP)), a);
            astf(&Ry[i], ry);                 // L3 atomic: next A reads row b
            blockMaxOut(ry, scratch, Pm3);
        }
        gridBarrier(slots, gen, rgen, bid, ++ep);
    }

    // ---------------- output (ry still in register) ----------------
    float m3 = blockMaxBcast(aldf(&Pm3[t]), scratch);
    float sf = (m3 > 1.0f) ? 1.0f / m3 : 1.0f;
    out[i] = sf * ry;
}

extern "C" void kernel_launch(void* const* d_in, const int* in_sizes, int n_in,
                              void* d_out, int out_size, void* d_ws, size_t ws_size,
                              hipStream_t stream) {
    const float* x = (const float*)d_in[0];   // (B,G)
    const float* W = (const float*)d_in[1];   // (M,C)
    const int*   I = (const int*)d_in[2];     // (C,G,S,L)
    float* out = (float*)d_out;

    // workspace layout (u32/f32 units)
    unsigned* slots = (unsigned*)d_ws;                 // 256*32 (128B/block)
    unsigned* gen   = slots + NBLK * 32;               // 32 (one line)
    unsigned* rgen  = gen + 32;                        // 17*32 relay lines
    float* Pm1 = (float*)(rgen + 17 * 32);             // 256
    float* Pm2 = Pm1 + NBLK;                           // 256
    float* Pm3 = Pm2 + NBLK;                           // 256
    float* Ry  = Pm3 + NBLK;                           // B*G
    unsigned* Ipk = (unsigned*)(Ry + (size_t)B * G);   // C*G*12 u32 (1.5MB)

    // Zero barrier state every replay (graph-capturable memset node).
    hipMemsetAsync(slots, 0, (NBLK * 32 + 32 + 17 * 32) * sizeof(unsigned),
                   stream);

    kmain<<<dim3(NBLK), dim3(NTHR), 0, stream>>>(
        x, W, I, slots, gen, rgen, Ipk, Pm1, Pm2, Pm3, Ry, out);
}

// Round 5
// 166.604 us; speedup vs baseline: 1.5622x; 1.0469x over previous
//
#include <hip/hip_runtime.h>

#define GAMMA 0.01f
#define B 32
#define G 2048
#define C 16
#define S 8
#define L 3
#define M 16
#define NBLK 256
#define NTHR 256
#define SLOT_STRIDE 16                // u64 per slot line (128 B)

// lse in base-2: exp(v/g) = exp2(v * K_EXP); g*log(s) = K_LOG * log2(s)
#define K_EXP 144.26950408889634f     // log2(e) / GAMMA
#define K_LOG 0.006931471805599453f   // GAMMA * ln(2)

#define SCOPE __HIP_MEMORY_SCOPE_AGENT

// Agent-scope relaxed atomics: executed at the L3 coherence point; no
// fences/cache flushes needed, L2 stays warm for read-only streams (Ipk).
__device__ __forceinline__ void ast(unsigned* p, unsigned v) {
    __hip_atomic_store(p, v, __ATOMIC_RELAXED, SCOPE);
}
__device__ __forceinline__ float aldf(const float* p) {
    return __hip_atomic_load(p, __ATOMIC_RELAXED, SCOPE);
}
__device__ __forceinline__ void astf(float* p, float v) {
    __hip_atomic_store(p, v, __ATOMIC_RELAXED, SCOPE);
}

__device__ __forceinline__ float waveMax(float v) {
#pragma unroll
    for (int off = 32; off > 0; off >>= 1)
        v = fmaxf(v, __shfl_xor(v, off, 64));
    return v;
}

// 256-thread block max, broadcast. Leading sync guards scratch reuse.
__device__ __forceinline__ float blockMaxBcast(float v, float* scratch) {
    float wm = waveMax(v);
    __syncthreads();
    if ((threadIdx.x & 63) == 0) scratch[threadIdx.x >> 6] = wm;
    __syncthreads();
    return fmaxf(fmaxf(scratch[0], scratch[1]), fmaxf(scratch[2], scratch[3]));
}

// Fused grid barrier + global max. Each block publishes {epoch, blockmax}
// as ONE u64 relaxed agent atomic (its own 128B line); every thread t of
// every block polls slot[t] (reads only -> no L3 contention), then an
// in-block reduction of the 256 payloads yields the global max. 2 L3 hops.
// Epoch-correctness: with 3 rotated arrays (A/B/C), writing X@e+1 requires
// passing two intervening all-block syncs, each needing every block past
// X@e -> a poller of X@e can never observe e+1's payload.
// Data visibility: the first __syncthreads drains every thread's global
// stores (compiler emits s_waitcnt vmcnt(0) before s_barrier), so t0's
// flag store is ordered after ALL the block's data stores at L3.
// Guard turns protocol bugs into wrong answers (verify), not hangs.
__device__ __forceinline__ float gridMaxBarrier(unsigned long long* slot,
                                                unsigned ep, float v,
                                                float* scratch) {
    float wm = waveMax(v);
    __syncthreads();                       // aligns block + drains stores
    if ((threadIdx.x & 63) == 0) scratch[threadIdx.x >> 6] = wm;
    __syncthreads();
    if (threadIdx.x == 0) {
        float bm = fmaxf(fmaxf(scratch[0], scratch[1]),
                         fmaxf(scratch[2], scratch[3]));
        unsigned long long pkt = ((unsigned long long)ep << 32) |
                                 (unsigned long long)__float_as_uint(bm);
        asm volatile("s_waitcnt vmcnt(0) lgkmcnt(0)" ::: "memory");
        __hip_atomic_store(&slot[(size_t)blockIdx.x * SLOT_STRIDE], pkt,
                           __ATOMIC_RELAXED, SCOPE);
    }
    unsigned long long got;
    int guard = 0;
    do {
        got = __hip_atomic_load(&slot[(size_t)threadIdx.x * SLOT_STRIDE],
                                __ATOMIC_RELAXED, SCOPE);
    } while ((unsigned)(got >> 32) < ep && ++guard < (1 << 17));
    return blockMaxBcast(__uint_as_float((unsigned)got), scratch);
}

// Persistent kernel, plain launch: 256 blocks x 256 threads (1 block/CU by
// construction: 8.8KB LDS, ~45 VGPR). Block bid -> (b = bid&31, gt = bid>>5).
// Thread owns one (b,g) for all 16 c's: h[16], hy, ry live in registers
// across phases; cross-block traffic = slot lines + Ry rows (L3 atomics).
extern "C" __global__ __launch_bounds__(256) void kmain(
    const float* __restrict__ x, const float* __restrict__ W,
    const int* __restrict__ I,
    unsigned long long* __restrict__ slotA, unsigned long long* __restrict__ slotB,
    unsigned long long* __restrict__ slotC, unsigned* __restrict__ Ipk,
    float* __restrict__ Ry, float* __restrict__ out)
{
    __shared__ __align__(16) float Vrow[G];   // 8 KB: s-scaled V row b
    __shared__ float WsL[C * M];              // transposed softmax(W)
    __shared__ float scratch[4];

    const int t = threadIdx.x;
    const int bid = blockIdx.x;
    const int b = bid & 31;
    const int gt = bid >> 5;
    const int g = (gt << 8) + t;
    const int i = b * G + g;

    // ---- init: per-block Ws (redundant, cheap) + pack I -> byte-offset pairs.
    // Ipk written via L3 atomics so fence-free remote plain reads (post-sync,
    // cold L2 at dispatch start) see it.
    {
        const int m = t >> 4, c = t & 15;
        float rmax = -INFINITY;
#pragma unroll
        for (int j = 0; j < C; j++) rmax = fmaxf(rmax, W[m * C + j]);
        float rsum = 0.f;
#pragma unroll
        for (int j = 0; j < C; j++) rsum += __expf(W[m * C + j] - rmax);
        WsL[c * M + m] = __expf(W[m * C + c] - rmax) / rsum;   // [c][m]
    }
    {
        const int tid = bid * NTHR + t;       // items (c,g): blocks 0-127
        if (tid < C * G) {
            const int4* ip4 = (const int4*)(I + (size_t)tid * 24);
            int idx[24];
#pragma unroll
            for (int j = 0; j < 6; j++) {
                int4 v = ip4[j];
                idx[4 * j + 0] = v.x; idx[4 * j + 1] = v.y;
                idx[4 * j + 2] = v.z; idx[4 * j + 3] = v.w;
            }
            unsigned* dst = Ipk + (size_t)tid * 12;
#pragma unroll
            for (int j = 0; j < 12; j++)      // byte offsets (idx*4), packed x2
                ast(&dst[j],
                    ((unsigned)idx[2 * j] << 2) | ((unsigned)idx[2 * j + 1] << 18));
        }
    }
    float m3 = gridMaxBarrier(slotC, 1, -INFINITY, scratch);   // init sync

    float ry = 0.f;
    for (int it = 0; it < 5; it++) {
        // ---------------- phase A: gather + lse_S + fused einsum --------------
        float s = 1.0f;
        if (it > 0)                           // uniform branch
            s = (m3 > 1.0f) ? 1.0f / m3 : 1.0f;
        if (it == 0) {                        // x: visible via dispatch acquire
            const float4* V4 = (const float4*)(x + (size_t)b * G);
            float4* Vr4 = (float4*)Vrow;
#pragma unroll
            for (int j = 0; j < 2; j++) Vr4[t + j * 256] = V4[t + j * 256];
        } else {                              // Ry: L3-atomic reads (coherent)
            const float* src = Ry + (size_t)b * G;
#pragma unroll
            for (int j = 0; j < 8; j++) {
                const int gg = t + j * 256;
                Vrow[gg] = s * aldf(&src[gg]);
            }
        }
        __syncthreads();

        float h[M];
#pragma unroll
        for (int m = 0; m < M; m++) h[m] = 0.f;
        float ymax = -INFINITY;
        const char* vb = (const char*)Vrow;

#pragma unroll 4
        for (int c = 0; c < C; c++) {
            const uint4* ip = (const uint4*)(Ipk + ((size_t)c * G + g) * 12);
            uint4 u0 = ip[0], u1 = ip[1], u2 = ip[2];
            unsigned w[12] = {u0.x, u0.y, u0.z, u0.w, u1.x, u1.y,
                              u1.z, u1.w, u2.x, u2.y, u2.z, u2.w};
            float vv[24];
#pragma unroll
            for (int q = 0; q < 12; q++) {    // 24 random LDS b32 gathers
                vv[2 * q]     = *(const float*)(vb + (w[q] & 0xffffu));
                vv[2 * q + 1] = *(const float*)(vb + (w[q] >> 16));
            }
            float body[S];
#pragma unroll
            for (int ss = 0; ss < S; ss++)
                body[ss] = vv[ss * 3] * vv[ss * 3 + 1] * vv[ss * 3 + 2];
            float bm = body[0];
#pragma unroll
            for (int ss = 1; ss < S; ss++) bm = fmaxf(bm, body[ss]);
            float sum = 0.f;
#pragma unroll
            for (int ss = 0; ss < S; ss++)
                sum += exp2f((body[ss] - bm) * K_EXP);
            float y = fmaf(K_LOG, log2f(sum), bm);   // unscaled Cv
            ymax = fmaxf(ymax, y);
#pragma unroll
            for (int m = 0; m < M; m++)       // s1 deferred (linear)
                h[m] = fmaf(WsL[c * M + m], y, h[m]);
        }
        float m1 = gridMaxBarrier(slotA, it + 1, ymax, scratch);

        // ---------------- phase B: s1-scale + lse_M (registers only) ----------
        float hy;
        {
            float s1 = (m1 > 1.0f) ? 1.0f / m1 : 1.0f;
            float hv[M];
            float hm = -INFINITY;
#pragma unroll
            for (int m = 0; m < M; m++) {
                hv[m] = s1 * h[m];
                hm = fmaxf(hm, hv[m]);
            }
            float sum = 0.f;
#pragma unroll
            for (int m = 0; m < M; m++) sum += exp2f((hv[m] - hm) * K_EXP);
            hy = fmaf(K_LOG, log2f(sum), hm);
        }
        float m2 = gridMaxBarrier(slotB, it + 1, hy, scratch);

        // ---------------- phase C: lse_2 with Rprev from LDS ------------------
        {
            float s2 = (m2 > 1.0f) ? 1.0f / m2 : 1.0f;
            float Rv = Vrow[g];               // = sp * Rprev (already scaled)
            float rv = s2 * hy;
            float a = fmaxf(Rv, rv), d = fminf(Rv, rv);
            ry = fmaf(K_LOG, log2f(1.0f + exp2f((d - a) * K_EXP)), a);
            astf(&Ry[i], ry);                 // L3 atomic: next A reads row b
        }
        m3 = gridMaxBarrier(slotC, it + 2, ry, scratch);
    }

    // ---------------- output (ry in register, m3 from last C-sync) ----------
    float sf = (m3 > 1.0f) ? 1.0f / m3 : 1.0f;
    out[i] = sf * ry;
}

extern "C" void kernel_launch(void* const* d_in, const int* in_sizes, int n_in,
                              void* d_out, int out_size, void* d_ws, size_t ws_size,
                              hipStream_t stream) {
    const float* x = (const float*)d_in[0];   // (B,G)
    const float* W = (const float*)d_in[1];   // (M,C)
    const int*   I = (const int*)d_in[2];     // (C,G,S,L)
    float* out = (float*)d_out;

    // workspace layout
    unsigned long long* slotA = (unsigned long long*)d_ws;   // 256*16 u64 (32KB)
    unsigned long long* slotB = slotA + NBLK * SLOT_STRIDE;  // 32KB
    unsigned long long* slotC = slotB + NBLK * SLOT_STRIDE;  // 32KB
    float* Ry = (float*)(slotC + NBLK * SLOT_STRIDE);        // B*G
    unsigned* Ipk = (unsigned*)(Ry + (size_t)B * G);         // C*G*12 u32 (1.5MB)

    // Zero barrier state every replay (graph-capturable memset node).
    hipMemsetAsync(slotA, 0, 3 * NBLK * SLOT_STRIDE * sizeof(unsigned long long),
                   stream);

    kmain<<<dim3(NBLK), dim3(NTHR), 0, stream>>>(
        x, W, I, slotA, slotB, slotC, Ipk, Ry, out);
}

// Round 7
// 160.425 us; speedup vs baseline: 1.6224x; 1.0385x over previous
//
#include <hip/hip_runtime.h>

#define GAMMA 0.01f
#define B 32
#define G 2048
#define C 16
#define S 8
#define L 3
#define M 16
#define NBLK 256
#define NTHR 512
#define SLOT_STRIDE 16                // u64 per slot line (128 B)

// lse in base-2: exp(v/g) = exp2(v * K_EXP); g*log(s) = K_LOG * log2(s)
#define K_EXP 144.26950408889634f     // log2(e) / GAMMA
#define K_LOG 0.006931471805599453f   // GAMMA * ln(2)

#define SCOPE __HIP_MEMORY_SCOPE_AGENT

// Agent-scope relaxed atomics: executed at the L3 coherence point; no
// fences/cache flushes, L2 stays warm for read-only streams (Ipk).
__device__ __forceinline__ void ast(unsigned* p, unsigned v) {
    __hip_atomic_store(p, v, __ATOMIC_RELAXED, SCOPE);
}
__device__ __forceinline__ float aldf(const float* p) {
    return __hip_atomic_load(p, __ATOMIC_RELAXED, SCOPE);
}
__device__ __forceinline__ void astf(float* p, float v) {
    __hip_atomic_store(p, v, __ATOMIC_RELAXED, SCOPE);
}

__device__ __forceinline__ float waveMax(float v) {
#pragma unroll
    for (int off = 32; off > 0; off >>= 1)
        v = fmaxf(v, __shfl_xor(v, off, 64));
    return v;
}

__device__ __forceinline__ float red8(const float* s) {
    return fmaxf(fmaxf(fmaxf(s[0], s[1]), fmaxf(s[2], s[3])),
                 fmaxf(fmaxf(s[4], s[5]), fmaxf(s[6], s[7])));
}

// Fused grid barrier + global max — round-5's PROVEN all-poll protocol,
// adapted to 8 waves. Each block publishes one u64 {epoch, blockmax} to its
// own 128B slot line (relaxed agent atomic). Every thread polls slot[t&255]
// (pure reads, no L3 contention), then an in-block reduce of the 256
// payloads yields the global max. 2 L3 hops.
// Epoch-correctness: 3 rotated arrays (A/B/C) — writing X@e+1 requires
// passing two intervening all-block syncs, each needing every block past
// X@e, so no poller of X@e can observe e+1's payload.
// Data visibility: per-thread vmcnt drain + __syncthreads before t0's
// packet store -> every thread's global stores are L3-complete first.
// Guards turn protocol bugs into wrong answers (verify), not hangs.
__device__ __forceinline__ float gridMaxBarrier(unsigned long long* slot,
                                                unsigned ep, float v,
                                                float* scratch) {
    asm volatile("s_waitcnt vmcnt(0) lgkmcnt(0)" ::: "memory");
    float wm = waveMax(v);
    __syncthreads();                       // aligns block; guards scratch reuse
    if ((threadIdx.x & 63) == 0) scratch[threadIdx.x >> 6] = wm;
    __syncthreads();
    if (threadIdx.x == 0) {
        float bm = red8(scratch);
        unsigned long long pkt = ((unsigned long long)ep << 32) |
                                 (unsigned long long)__float_as_uint(bm);
        __hip_atomic_store(&slot[(size_t)blockIdx.x * SLOT_STRIDE], pkt,
                           __ATOMIC_RELAXED, SCOPE);
    }
    unsigned long long got;
    int guard = 0;
    do {
        got = __hip_atomic_load(
            &slot[(size_t)(threadIdx.x & 255) * SLOT_STRIDE],
            __ATOMIC_RELAXED, SCOPE);
    } while ((unsigned)(got >> 32) < ep && ++guard < (1 << 17));
    float pv = waveMax(__uint_as_float((unsigned)got));
    __syncthreads();
    if ((threadIdx.x & 63) == 0) scratch[threadIdx.x >> 6] = pv;
    __syncthreads();
    return red8(scratch);
}

// Persistent kernel, plain launch: 256 blocks x 512 threads = 1 block/CU
// (proven-resident geometry), 8 waves = 2 waves/SIMD (2x round 5's 1/SIMD).
// Block bid -> (b = bid&31, gt = bid>>5): row b, g in [gt*256, gt*256+256).
// Phase A: thread (ch = t>>8, gl = t&255) handles 8 c's for its g; partial
// h[16] combined via LDS stride-33 (2-way bank conflicts = free).
// Phases B/C: threads t<256 own (b,g) 1:1; hy/ry in registers.
extern "C" __global__ __launch_bounds__(512, 2) void kmain(
    const float* __restrict__ x, const float* __restrict__ W,
    const int* __restrict__ I,
    unsigned long long* __restrict__ slotA, unsigned long long* __restrict__ slotB,
    unsigned long long* __restrict__ slotC, unsigned* __restrict__ Ipk,
    float* __restrict__ Ry, float* __restrict__ out)
{
    __shared__ __align__(16) float Vrow[G];   // 8 KB: s-scaled V row b
    __shared__ float WsL[C * M];              // transposed softmax(W)
    __shared__ float ph[256 * 33];            // 33 KB partial-h combine
    __shared__ float scratch[8];

    const int t = threadIdx.x;
    const int bid = blockIdx.x;
    const int b = bid & 31;
    const int gt = bid >> 5;
    const int ch = t >> 8;                    // c-half (phase A)
    const int gl = t & 255;
    const int g = (gt << 8) + gl;

    // ---- init: per-block Ws (redundant, cheap) + pack I -> byte-offset pairs.
    // Ipk via L3 atomics (fence-free remote plain reads see L3).
    if (t < 256) {
        const int m = t >> 4, c = t & 15;
        float rmax = -INFINITY;
#pragma unroll
        for (int j = 0; j < C; j++) rmax = fmaxf(rmax, W[m * C + j]);
        float rsum = 0.f;
#pragma unroll
        for (int j = 0; j < C; j++) rsum += __expf(W[m * C + j] - rmax);
        WsL[c * M + m] = __expf(W[m * C + c] - rmax) / rsum;   // [c][m]
    }
    {
        const int tid = bid * NTHR + t;       // items (c,g): blocks 0-63
        if (tid < C * G) {
            const int4* ip4 = (const int4*)(I + (size_t)tid * 24);
            int idx[24];
#pragma unroll
            for (int j = 0; j < 6; j++) {
                int4 v = ip4[j];
                idx[4 * j + 0] = v.x; idx[4 * j + 1] = v.y;
                idx[4 * j + 2] = v.z; idx[4 * j + 3] = v.w;
            }
            unsigned* dst = Ipk + (size_t)tid * 12;
#pragma unroll
            for (int j = 0; j < 12; j++)      // byte offsets (idx*4), packed x2
                ast(&dst[j],
                    ((unsigned)idx[2 * j] << 2) | ((unsigned)idx[2 * j + 1] << 18));
        }
    }
    float m3 = gridMaxBarrier(slotC, 1, -INFINITY, scratch);   // init sync

    float ry = 0.f;
    for (int it = 0; it < 5; it++) {
        // ---------------- phase A: gather + lse_S + fused einsum --------------
        float s = 1.0f;
        if (it > 0)                           // uniform branch
            s = (m3 > 1.0f) ? 1.0f / m3 : 1.0f;
        if (it == 0) {                        // x visible via dispatch
            const float4* V4 = (const float4*)(x + (size_t)b * G);
            ((float4*)Vrow)[t] = V4[t];       // 512 float4 = full row
        } else {                              // Ry: L3-atomic reads (coherent)
            const float* src = Ry + (size_t)b * G;
#pragma unroll
            for (int j = 0; j < 4; j++) {
                const int gg = t + j * 512;
                Vrow[gg] = s * aldf(&src[gg]);
            }
        }
        __syncthreads();

        float h[M];
#pragma unroll
        for (int m = 0; m < M; m++) h[m] = 0.f;
        float ymax = -INFINITY;
        const char* vb = (const char*)Vrow;

#pragma unroll 2
        for (int cc = 0; cc < 8; cc++) {      // this thread's 8 c's
            const int c = ch * 8 + cc;
            const uint4* ip = (const uint4*)(Ipk + ((size_t)c * G + g) * 12);
            uint4 u0 = ip[0], u1 = ip[1], u2 = ip[2];
            unsigned w[12] = {u0.x, u0.y, u0.z, u0.w, u1.x, u1.y,
                              u1.z, u1.w, u2.x, u2.y, u2.z, u2.w};
            float vv[24];
#pragma unroll
            for (int q = 0; q < 12; q++) {    // 24 random LDS b32 gathers
                vv[2 * q]     = *(const float*)(vb + (w[q] & 0xffffu));
                vv[2 * q + 1] = *(const float*)(vb + (w[q] >> 16));
            }
            float body[S];
#pragma unroll
            for (int ss = 0; ss < S; ss++)
                body[ss] = vv[ss * 3] * vv[ss * 3 + 1] * vv[ss * 3 + 2];
            float bm = body[0];
#pragma unroll
            for (int ss = 1; ss < S; ss++) bm = fmaxf(bm, body[ss]);
            float sum = 0.f;
#pragma unroll
            for (int ss = 0; ss < S; ss++)
                sum += exp2f((body[ss] - bm) * K_EXP);
            float y = fmaf(K_LOG, log2f(sum), bm);   // unscaled Cv
            ymax = fmaxf(ymax, y);
#pragma unroll
            for (int m = 0; m < M; m++)       // s1 deferred (linear)
                h[m] = fmaf(WsL[c * M + m], y, h[m]);
        }
        // partial h -> LDS; bank = (gl + chunk) mod 32 -> 2-way = free
#pragma unroll
        for (int m = 0; m < M; m++)
            ph[gl * 33 + ch * 16 + m] = h[m];
        float m1 = gridMaxBarrier(slotA, it + 1, ymax, scratch);

        // ---------------- phase B: combine + s1-scale + lse_M -----------------
        float hy = -INFINITY;
        if (t < 256) {
            float s1 = (m1 > 1.0f) ? 1.0f / m1 : 1.0f;
            float hv[M];
            float hm = -INFINITY;
#pragma unroll
            for (int m = 0; m < M; m++) {
                float hh = ph[t * 33 + m] + ph[t * 33 + 16 + m];
                hv[m] = s1 * hh;
                hm = fmaxf(hm, hv[m]);
            }
            float sum = 0.f;
#pragma unroll
            for (int m = 0; m < M; m++) sum += exp2f((hv[m] - hm) * K_EXP);
            hy = fmaf(K_LOG, log2f(sum), hm);
        }
        float m2 = gridMaxBarrier(slotB, it + 1, hy, scratch);

        // ---------------- phase C: lse_2 with Rprev from LDS ------------------
        float rt = -INFINITY;
        if (t < 256) {
            float s2 = (m2 > 1.0f) ? 1.0f / m2 : 1.0f;
            float Rv = Vrow[(gt << 8) + t];   // = sp * Rprev (already scaled)
            float rv = s2 * hy;
            float a = fmaxf(Rv, rv), d = fminf(Rv, rv);
            ry = fmaf(K_LOG, log2f(1.0f + exp2f((d - a) * K_EXP)), a);
            astf(&Ry[(size_t)b * G + (gt << 8) + t], ry);  // next A reads row b
            rt = ry;
        }
        m3 = gridMaxBarrier(slotC, it + 2, rt, scratch);
    }

    // ---------------- output (ry in register, m3 from last C-sync) ----------
    if (t < 256) {
        float sf = (m3 > 1.0f) ? 1.0f / m3 : 1.0f;
        out[(size_t)b * G + (gt << 8) + t] = sf * ry;
    }
}

extern "C" void kernel_launch(void* const* d_in, const int* in_sizes, int n_in,
                              void* d_out, int out_size, void* d_ws, size_t ws_size,
                              hipStream_t stream) {
    const float* x = (const float*)d_in[0];   // (B,G)
    const float* W = (const float*)d_in[1];   // (M,C)
    const int*   I = (const int*)d_in[2];     // (C,G,S,L)
    float* out = (float*)d_out;

    // workspace layout
    unsigned long long* slotA = (unsigned long long*)d_ws;   // 256*16 u64 (32KB)
    unsigned long long* slotB = slotA + NBLK * SLOT_STRIDE;  // 32KB
    unsigned long long* slotC = slotB + NBLK * SLOT_STRIDE;  // 32KB
    float* Ry = (float*)(slotC + NBLK * SLOT_STRIDE);        // B*G
    unsigned* Ipk = (unsigned*)(Ry + (size_t)B * G);         // C*G*12 u32 (1.5MB)

    // Zero barrier state every replay (graph-capturable memset node).
    hipMemsetAsync(slotA, 0, 3 * NBLK * SLOT_STRIDE * sizeof(unsigned long long),
                   stream);

    kmain<<<dim3(NBLK), dim3(NTHR), 0, stream>>>(
        x, W, I, slotA, slotB, slotC, Ipk, Ry, out);
}

// Round 8
// 145.963 us; speedup vs baseline: 1.7831x; 1.0991x over previous
//
#include <hip/hip_runtime.h>

#define GAMMA 0.01f
#define B 32
#define G 2048
#define C 16
#define S 8
#define L 3
#define M 16
#define NBLK 256
#define NTHR 512
#define GSTR 16                       // u64 stride for gslot lines (128 B)

// lse in base-2: exp(v/g) = exp2(v * K_EXP); g*log(s) = K_LOG * log2(s)
#define K_EXP 144.26950408889634f     // log2(e) / GAMMA
#define K_LOG 0.006931471805599453f   // GAMMA * ln(2)

#define SCOPE __HIP_MEMORY_SCOPE_AGENT

// Agent-scope relaxed atomics: executed at the L3 coherence point; no
// fences/cache flushes, L2 stays warm for read-only streams (Ipk).
__device__ __forceinline__ void ast(unsigned* p, unsigned v) {
    __hip_atomic_store(p, v, __ATOMIC_RELAXED, SCOPE);
}
__device__ __forceinline__ float aldf(const float* p) {
    return __hip_atomic_load(p, __ATOMIC_RELAXED, SCOPE);
}
__device__ __forceinline__ void astf(float* p, float v) {
    __hip_atomic_store(p, v, __ATOMIC_RELAXED, SCOPE);
}
__device__ __forceinline__ unsigned long long ald64(const unsigned long long* p) {
    return __hip_atomic_load(p, __ATOMIC_RELAXED, SCOPE);
}
__device__ __forceinline__ void ast64(unsigned long long* p, unsigned long long v) {
    __hip_atomic_store(p, v, __ATOMIC_RELAXED, SCOPE);
}

__device__ __forceinline__ float waveMax(float v) {
#pragma unroll
    for (int off = 32; off > 0; off >>= 1)
        v = fmaxf(v, __shfl_xor(v, off, 64));
    return v;
}

__device__ __forceinline__ float red8(const float* s) {
    return fmaxf(fmaxf(fmaxf(s[0], s[1]), fmaxf(s[2], s[3])),
                 fmaxf(fmaxf(s[4], s[5]), fmaxf(s[6], s[7])));
}

// ---- hierarchical grid barrier + global max (3 hops, low poll traffic) ----
// arrive: per-thread vmcnt drain; block max -> one u64 {epoch, blockmax}
// stored to CONTIGUOUS slot[bid]. No waiting.
__device__ __forceinline__ void barArrive(unsigned long long* slot, unsigned ep,
                                          float v, float* scratch) {
    asm volatile("s_waitcnt vmcnt(0) lgkmcnt(0)" ::: "memory");
    float wm = waveMax(v);
    __syncthreads();                  // all threads drained; guards scratch
    if ((threadIdx.x & 63) == 0) scratch[threadIdx.x >> 6] = wm;
    __syncthreads();
    if (threadIdx.x == 0) {
        float bm = red8(scratch);
        ast64(&slot[blockIdx.x], ((unsigned long long)ep << 32) |
                                 (unsigned long long)__float_as_uint(bm));
    }
}

// wait: 16 leaders (bid%16==0) relay: wave0 lanes 0-15 poll the group's 16
// contiguous slots in parallel, waveMax, lane0 stores {ep, groupmax} to its
// padded gslot line. ALL blocks: wave0 lanes 0-15 poll the 16 gslot lines,
// waveMax -> global max. Poll streams ~4K on 18 lines (no L3 storm).
// Rotation (A/B/C arrays incl. gslot): re-writing X@e+1 requires passing two
// intervening full barriers, each needing every block departed X@e -> no
// poller of X@e can observe e+1. Guards: bugs -> wrong answer, not hang.
__device__ __forceinline__ float barWait(const unsigned long long* slot,
                                         unsigned long long* gslot,
                                         unsigned ep, float* scratch) {
    const int t = threadIdx.x;
    if (t < 64) {
        if ((blockIdx.x & 15) == 0) {         // leader relay (block-uniform)
            float pv = -INFINITY;
            if (t < 16) {
                unsigned long long got;
                int guard = 0;
                do { got = ald64(&slot[blockIdx.x + t]); }
                while ((unsigned)(got >> 32) < ep && ++guard < (1 << 17));
                pv = __uint_as_float((unsigned)got);
            }
            float gm = waveMax(pv);
            if (t == 0)
                ast64(&gslot[(size_t)(blockIdx.x >> 4) * GSTR],
                      ((unsigned long long)ep << 32) |
                      (unsigned long long)__float_as_uint(gm));
        }
        float qv = -INFINITY;
        if (t < 16) {
            unsigned long long got;
            int guard = 0;
            do { got = ald64(&gslot[(size_t)t * GSTR]); }
            while ((unsigned)(got >> 32) < ep && ++guard < (1 << 17));
            qv = __uint_as_float((unsigned)got);
        }
        float fm = waveMax(qv);
        if (t == 0) scratch[0] = fm;
    }
    __syncthreads();
    return scratch[0];
}

// Persistent kernel, plain launch: 256 blocks x 512 threads = 1 block/CU,
// 8 waves = 2 waves/SIMD (r7's proven geometry). Block bid -> (b = bid&31,
// gt = bid>>5). Phase A: thread (ch = t>>8, gl = t&255) handles 8 c's for its
// g; partial h[16] combined via LDS stride-33. Phases B/C: t<256 own (b,g).
extern "C" __global__ __launch_bounds__(512, 2) void kmain(
    const float* __restrict__ x, const float* __restrict__ W,
    const int* __restrict__ I,
    unsigned long long* __restrict__ slotA, unsigned long long* __restrict__ slotB,
    unsigned long long* __restrict__ slotC, unsigned long long* __restrict__ gslotA,
    unsigned long long* __restrict__ gslotB, unsigned long long* __restrict__ gslotC,
    unsigned* __restrict__ Ipk, float* __restrict__ Ry, float* __restrict__ out)
{
    __shared__ __align__(16) float Vrow[G];   // 8 KB: s-scaled V row b
    __shared__ __align__(16) float WsL[C * M]; // transposed softmax(W), [c][m]
    __shared__ float ph[256 * 33];            // 33 KB partial-h combine
    __shared__ float scratch[8];

    const int t = threadIdx.x;
    const int bid = blockIdx.x;
    const int b = bid & 31;
    const int gt = bid >> 5;
    const int ch = t >> 8;                    // c-half (phase A)
    const int gl = t & 255;
    const int g = (gt << 8) + gl;

    // ---- init: per-block Ws (redundant, cheap) + pack I -> byte-offset pairs.
    // Ipk via L3 atomics (fence-free remote plain reads see L3).
    if (t < 256) {
        const int m = t >> 4, c = t & 15;
        float rmax = -INFINITY;
#pragma unroll
        for (int j = 0; j < C; j++) rmax = fmaxf(rmax, W[m * C + j]);
        float rsum = 0.f;
#pragma unroll
        for (int j = 0; j < C; j++) rsum += __expf(W[m * C + j] - rmax);
        WsL[c * M + m] = __expf(W[m * C + c] - rmax) / rsum;   // [c][m]
    }
    {
        const int tid = bid * NTHR + t;       // items (c,g): blocks 0-63
        if (tid < C * G) {
            const int4* ip4 = (const int4*)(I + (size_t)tid * 24);
            int idx[24];
#pragma unroll
            for (int j = 0; j < 6; j++) {
                int4 v = ip4[j];
                idx[4 * j + 0] = v.x; idx[4 * j + 1] = v.y;
                idx[4 * j + 2] = v.z; idx[4 * j + 3] = v.w;
            }
            unsigned* dst = Ipk + (size_t)tid * 12;
#pragma unroll
            for (int j = 0; j < 12; j++)      // byte offsets (idx*4), packed x2
                ast(&dst[j],
                    ((unsigned)idx[2 * j] << 2) | ((unsigned)idx[2 * j + 1] << 18));
        }
    }
    barArrive(slotC, 1, -INFINITY, scratch);
    float m3 = barWait(slotC, gslotC, 1, scratch);   // init sync

    float ry = 0.f;
    for (int it = 0; it < 5; it++) {
        // ---------------- phase A: gather + lse_S + fused einsum --------------
        float s = 1.0f;
        if (it > 0)                           // uniform branch
            s = (m3 > 1.0f) ? 1.0f / m3 : 1.0f;
        if (it == 0) {                        // x visible via dispatch
            const float4* V4 = (const float4*)(x + (size_t)b * G);
            ((float4*)Vrow)[t] = V4[t];       // 512 float4 = full row
        } else {                              // Ry: L3-atomic reads (coherent)
            const float* src = Ry + (size_t)b * G;
#pragma unroll
            for (int j = 0; j < 4; j++) {
                const int gg = t + j * 512;
                Vrow[gg] = s * aldf(&src[gg]);
            }
        }
        __syncthreads();

        float h[M];
#pragma unroll
        for (int m = 0; m < M; m++) h[m] = 0.f;
        float ymax = -INFINITY;
        const char* vb = (const char*)Vrow;

#pragma unroll 2
        for (int cc = 0; cc < 8; cc++) {      // this thread's 8 c's
            const int c = ch * 8 + cc;
            const uint4* ip = (const uint4*)(Ipk + ((size_t)c * G + g) * 12);
            uint4 u0 = ip[0], u1 = ip[1], u2 = ip[2];
            unsigned w[12] = {u0.x, u0.y, u0.z, u0.w, u1.x, u1.y,
                              u1.z, u1.w, u2.x, u2.y, u2.z, u2.w};
            float vv[24];
#pragma unroll
            for (int q = 0; q < 12; q++) {    // 24 random LDS b32 gathers
                vv[2 * q]     = *(const float*)(vb + (w[q] & 0xffffu));
                vv[2 * q + 1] = *(const float*)(vb + (w[q] >> 16));
            }
            float body[S];
#pragma unroll
            for (int ss = 0; ss < S; ss++)
                body[ss] = vv[ss * 3] * vv[ss * 3 + 1] * vv[ss * 3 + 2];
            float bm = body[0];
#pragma unroll
            for (int ss = 1; ss < S; ss++) bm = fmaxf(bm, body[ss]);
            float sum = 0.f;
#pragma unroll
            for (int ss = 0; ss < S; ss++)
                sum += exp2f((body[ss] - bm) * K_EXP);
            float y = fmaf(K_LOG, log2f(sum), bm);   // unscaled Cv
            ymax = fmaxf(ymax, y);
            // fused einsum via float4 WsL reads (4 x ds_read_b128, not 16 b32)
            const float4* Wc = (const float4*)&WsL[c * M];
            float4 w0 = Wc[0], w1 = Wc[1], w2 = Wc[2], w3 = Wc[3];
            const float wv[16] = {w0.x, w0.y, w0.z, w0.w, w1.x, w1.y, w1.z, w1.w,
                                  w2.x, w2.y, w2.z, w2.w, w3.x, w3.y, w3.z, w3.w};
#pragma unroll
            for (int m = 0; m < M; m++)       // s1 deferred (linear)
                h[m] = fmaf(wv[m], y, h[m]);
        }
        // partial h -> LDS; bank = (gl + chunk) mod 32 -> 2-way = free
#pragma unroll
        for (int m = 0; m < M; m++)
            ph[gl * 33 + ch * 16 + m] = h[m];
        barArrive(slotA, it + 1, ymax, scratch);
        // overlap: m1-independent combine reads (ph writes covered by arrive's
        // two syncthreads)
        float hraw[M];
        if (t < 256) {
#pragma unroll
            for (int m = 0; m < M; m++)
                hraw[m] = ph[t * 33 + m] + ph[t * 33 + 16 + m];
        }
        float m1 = barWait(slotA, gslotA, it + 1, scratch);

        // ---------------- phase B: s1-scale + lse_M (registers only) ----------
        float hy = -INFINITY;
        if (t < 256) {
            float s1 = (m1 > 1.0f) ? 1.0f / m1 : 1.0f;
            float hv[M];
            float hm = -INFINITY;
#pragma unroll
            for (int m = 0; m < M; m++) {
                hv[m] = s1 * hraw[m];
                hm = fmaxf(hm, hv[m]);
            }
            float sum = 0.f;
#pragma unroll
            for (int m = 0; m < M; m++) sum += exp2f((hv[m] - hm) * K_EXP);
            hy = fmaf(K_LOG, log2f(sum), hm);
        }
        barArrive(slotB, it + 1, hy, scratch);
        float Rv = (t < 256) ? Vrow[(gt << 8) + t] : 0.f;  // m2-independent
        float m2 = barWait(slotB, gslotB, it + 1, scratch);

        // ---------------- phase C: lse_2 with Rprev from LDS ------------------
        float rt = -INFINITY;
        if (t < 256) {
            float s2 = (m2 > 1.0f) ? 1.0f / m2 : 1.0f;
            float rv = s2 * hy;                // Rv = sp*Rprev (already scaled)
            float a = fmaxf(Rv, rv), d = fminf(Rv, rv);
            ry = fmaf(K_LOG, log2f(1.0f + exp2f((d - a) * K_EXP)), a);
            astf(&Ry[(size_t)b * G + (gt << 8) + t], ry);  // next A reads row b
            rt = ry;
        }
        barArrive(slotC, it + 2, rt, scratch);
        m3 = barWait(slotC, gslotC, it + 2, scratch);
    }

    // ---------------- output (ry in register, m3 from last C-sync) ----------
    if (t < 256) {
        float sf = (m3 > 1.0f) ? 1.0f / m3 : 1.0f;
        out[(size_t)b * G + (gt << 8) + t] = sf * ry;
    }
}

extern "C" void kernel_launch(void* const* d_in, const int* in_sizes, int n_in,
                              void* d_out, int out_size, void* d_ws, size_t ws_size,
                              hipStream_t stream) {
    const float* x = (const float*)d_in[0];   // (B,G)
    const float* W = (const float*)d_in[1];   // (M,C)
    const int*   I = (const int*)d_in[2];     // (C,G,S,L)
    float* out = (float*)d_out;

    // workspace layout (u64 units first)
    unsigned long long* slotA  = (unsigned long long*)d_ws;  // 256 u64 (2 KB)
    unsigned long long* slotB  = slotA + NBLK;               // 2 KB
    unsigned long long* slotC  = slotB + NBLK;               // 2 KB
    unsigned long long* gslotA = slotC + NBLK;               // 16*GSTR u64 (2 KB)
    unsigned long long* gslotB = gslotA + 16 * GSTR;         // 2 KB
    unsigned long long* gslotC = gslotB + 16 * GSTR;         // 2 KB
    float* Ry = (float*)(gslotC + 16 * GSTR);                // B*G
    unsigned* Ipk = (unsigned*)(Ry + (size_t)B * G);         // C*G*12 u32 (1.5MB)

    // Zero barrier state every replay (graph-capturable memset node).
    hipMemsetAsync(slotA, 0, (3 * NBLK + 3 * 16 * GSTR) * sizeof(unsigned long long),
                   stream);

    kmain<<<dim3(NBLK), dim3(NTHR), 0, stream>>>(
        x, W, I, slotA, slotB, slotC, gslotA, gslotB, gslotC, Ipk, Ry, out);
}